// Round 1
// baseline (3025.416 us; speedup 1.0000x reference)
//
#include <hip/hip_runtime.h>
#include <cstddef>

#define BATCH   8
#define SEQ     1024
#define DMODEL  1024
#define NHEADS  16
#define DKH     64
#define MROWS   (BATCH*SEQ)   // 8192

// ---------------------------------------------------------------------------
// Generic f32 GEMM:  C = A(MxK) * W^T (+ bias), W is [N][K] row-major.
// proj_layout=1: write C[b,h,s,dk] (attention layout); else row-major [M][N].
// 64x64 tile, BK=16, 256 threads, 4x4 outputs per thread.
// ---------------------------------------------------------------------------
#define BM 64
#define BN 64
#define BKT 16

__global__ __launch_bounds__(256)
void gemm_bias_kernel(const float* __restrict__ A, const float* __restrict__ W,
                      const float* __restrict__ bias, float* __restrict__ C,
                      int proj_layout)
{
    __shared__ float As[BKT][BM + 1];
    __shared__ float Ws[BKT][BN + 1];

    const int tid = threadIdx.x;
    const int m0 = blockIdx.y * BM;
    const int n0 = blockIdx.x * BN;
    const int tx = tid & 15;
    const int ty = tid >> 4;

    const int idx = tid * 4;
    const int lr = idx >> 4;   // 0..63 row within tile
    const int lk = idx & 15;   // 0,4,8,12

    float acc[4][4] = {{0.f, 0.f, 0.f, 0.f}, {0.f, 0.f, 0.f, 0.f},
                       {0.f, 0.f, 0.f, 0.f}, {0.f, 0.f, 0.f, 0.f}};

    for (int k0 = 0; k0 < DMODEL; k0 += BKT) {
        const float4 av = *reinterpret_cast<const float4*>(
            &A[(size_t)(m0 + lr) * DMODEL + k0 + lk]);
        const float4 wv = *reinterpret_cast<const float4*>(
            &W[(size_t)(n0 + lr) * DMODEL + k0 + lk]);
        As[lk + 0][lr] = av.x; As[lk + 1][lr] = av.y;
        As[lk + 2][lr] = av.z; As[lk + 3][lr] = av.w;
        Ws[lk + 0][lr] = wv.x; Ws[lk + 1][lr] = wv.y;
        Ws[lk + 2][lr] = wv.z; Ws[lk + 3][lr] = wv.w;
        __syncthreads();

        #pragma unroll
        for (int kk = 0; kk < BKT; ++kk) {
            float a[4], b[4];
            #pragma unroll
            for (int i = 0; i < 4; ++i) a[i] = As[kk][ty * 4 + i];
            #pragma unroll
            for (int j = 0; j < 4; ++j) b[j] = Ws[kk][tx * 4 + j];
            #pragma unroll
            for (int i = 0; i < 4; ++i)
                #pragma unroll
                for (int j = 0; j < 4; ++j)
                    acc[i][j] = fmaf(a[i], b[j], acc[i][j]);
        }
        __syncthreads();
    }

    #pragma unroll
    for (int i = 0; i < 4; ++i) {
        const int row = m0 + ty * 4 + i;
        const int b = row >> 10;       // /SEQ
        const int s = row & 1023;      // %SEQ
        #pragma unroll
        for (int j = 0; j < 4; ++j) {
            const int col = n0 + tx * 4 + j;
            const float v = acc[i][j] + bias[col];
            if (proj_layout) {
                const int h = col >> 6;
                const int di = col & 63;
                C[(((size_t)(b * NHEADS + h)) * SEQ + s) * DKH + di] = v;
            } else {
                C[(size_t)row * DMODEL + col] = v;
            }
        }
    }
}

// ---------------------------------------------------------------------------
// Attention pass 1: per (b,h, 32-row q tile), compute masked scaled scores,
// write RAW scores into the p_attn output region, track online row max/sum.
// Block 256 threads: thread (q = tid/8, c = tid%8) owns 8 k-columns.
// ---------------------------------------------------------------------------
#define QB 32
#define KB 64

__global__ __launch_bounds__(256)
void attn_score_kernel(const float* __restrict__ qbuf, const float* __restrict__ kbuf,
                       const int* __restrict__ mask, float* __restrict__ pattn,
                       float* __restrict__ rowmax, float* __restrict__ rowsum)
{
    const int blk = blockIdx.x;
    const int qt = blk & 31;          // S/QB = 32 tiles
    const int bh = blk >> 5;          // 0..127
    const int b = bh >> 4;
    const int q0 = qt * QB;

    __shared__ float Qs[QB][DKH + 1];
    __shared__ float Ks[KB][DKH + 1];
    __shared__ int mqs[QB];
    __shared__ int mks[KB];

    const int tid = threadIdx.x;

    // Load Q tile (32x64): 8 consecutive floats per thread.
    {
        const int row = tid >> 3;
        const int c0 = (tid & 7) * 8;
        const float* src = &qbuf[((size_t)bh * SEQ + q0 + row) * DKH + c0];
        const float4 v0 = *reinterpret_cast<const float4*>(src);
        const float4 v1 = *reinterpret_cast<const float4*>(src + 4);
        Qs[row][c0 + 0] = v0.x; Qs[row][c0 + 1] = v0.y;
        Qs[row][c0 + 2] = v0.z; Qs[row][c0 + 3] = v0.w;
        Qs[row][c0 + 4] = v1.x; Qs[row][c0 + 5] = v1.y;
        Qs[row][c0 + 6] = v1.z; Qs[row][c0 + 7] = v1.w;
    }
    if (tid < QB) mqs[tid] = mask[b * SEQ + q0 + tid];

    const int q = tid >> 3;
    const int c = tid & 7;

    float rm = -3.0e38f;
    float rl = 0.f;

    for (int kt = 0; kt < SEQ / KB; ++kt) {
        __syncthreads();   // Ks reuse-safe (and Qs visible on first iter)
        {
            const int row = tid >> 2;          // 0..63
            const int c0 = (tid & 3) * 16;
            const float* src = &kbuf[((size_t)bh * SEQ + kt * KB + row) * DKH + c0];
            const float4 v0 = *reinterpret_cast<const float4*>(src);
            const float4 v1 = *reinterpret_cast<const float4*>(src + 4);
            const float4 v2 = *reinterpret_cast<const float4*>(src + 8);
            const float4 v3 = *reinterpret_cast<const float4*>(src + 12);
            Ks[row][c0 + 0] = v0.x;  Ks[row][c0 + 1] = v0.y;
            Ks[row][c0 + 2] = v0.z;  Ks[row][c0 + 3] = v0.w;
            Ks[row][c0 + 4] = v1.x;  Ks[row][c0 + 5] = v1.y;
            Ks[row][c0 + 6] = v1.z;  Ks[row][c0 + 7] = v1.w;
            Ks[row][c0 + 8] = v2.x;  Ks[row][c0 + 9] = v2.y;
            Ks[row][c0 + 10] = v2.z; Ks[row][c0 + 11] = v2.w;
            Ks[row][c0 + 12] = v3.x; Ks[row][c0 + 13] = v3.y;
            Ks[row][c0 + 14] = v3.z; Ks[row][c0 + 15] = v3.w;
        }
        if (tid < KB) mks[tid] = mask[b * SEQ + kt * KB + tid];
        __syncthreads();

        float s[8];
        #pragma unroll
        for (int i = 0; i < 8; ++i) s[i] = 0.f;
        for (int d = 0; d < DKH; ++d) {
            const float qd = Qs[q][d];
            #pragma unroll
            for (int i = 0; i < 8; ++i)
                s[i] = fmaf(qd, Ks[c * 8 + i][d], s[i]);
        }
        const int mq = mqs[q];
        #pragma unroll
        for (int i = 0; i < 8; ++i)
            s[i] = (mq && mks[c * 8 + i]) ? s[i] * 0.125f : -1e9f;

        {   // write raw masked scores into the p_attn region (scratch use)
            float* dst = &pattn[((size_t)bh * SEQ + q0 + q) * SEQ + kt * KB + c * 8];
            *reinterpret_cast<float4*>(dst) = make_float4(s[0], s[1], s[2], s[3]);
            *reinterpret_cast<float4*>(dst + 4) = make_float4(s[4], s[5], s[6], s[7]);
        }

        // Online row max/sum over the 8-lane group owning this q-row.
        float tmax = s[0];
        #pragma unroll
        for (int i = 1; i < 8; ++i) tmax = fmaxf(tmax, s[i]);
        #pragma unroll
        for (int o = 1; o < 8; o <<= 1) tmax = fmaxf(tmax, __shfl_xor(tmax, o, 8));
        const float nm = fmaxf(rm, tmax);
        float ps = 0.f;
        #pragma unroll
        for (int i = 0; i < 8; ++i) ps += expf(s[i] - nm);
        #pragma unroll
        for (int o = 1; o < 8; o <<= 1) ps += __shfl_xor(ps, o, 8);
        rl = rl * expf(rm - nm) + ps;
        rm = nm;
    }

    if (c == 0) {
        rowmax[(size_t)bh * SEQ + q0 + q] = rm;
        rowsum[(size_t)bh * SEQ + q0 + q] = rl;
    }
}

// ---------------------------------------------------------------------------
// Attention pass 2: normalize scores -> final p_attn (write back in place),
// accumulate x = p @ V, store x in (b, s, H*dk) layout for the output GEMM.
// Thread (q = tid/8, db = (tid%8)*8) owns 8 output dims of one q-row.
// ---------------------------------------------------------------------------
__global__ __launch_bounds__(256)
void attn_pv_kernel(const float* __restrict__ vbuf, const int* __restrict__ mask,
                    float* __restrict__ pattn, const float* __restrict__ rowmax,
                    const float* __restrict__ rowsum, float* __restrict__ xbuf)
{
    const int blk = blockIdx.x;
    const int qt = blk & 31;
    const int bh = blk >> 5;
    const int b = bh >> 4;
    const int h = bh & 15;
    const int q0 = qt * QB;

    __shared__ float Ps[QB][KB + 1];
    __shared__ float Vs[KB][DKH + 1];
    __shared__ float rms[QB];
    __shared__ float rls[QB];
    __shared__ int mqs[QB];

    const int tid = threadIdx.x;
    if (tid < QB) {
        rms[tid] = rowmax[(size_t)bh * SEQ + q0 + tid];
        rls[tid] = rowsum[(size_t)bh * SEQ + q0 + tid];
        mqs[tid] = mask[b * SEQ + q0 + tid];
    }

    const int q = tid >> 3;
    const int c = tid & 7;
    const int db = c * 8;

    float xacc[8];
    #pragma unroll
    for (int j = 0; j < 8; ++j) xacc[j] = 0.f;

    for (int kt = 0; kt < SEQ / KB; ++kt) {
        __syncthreads();   // Ps/Vs reuse-safe; rms visible on first iter
        {
            float* srcdst = &pattn[((size_t)bh * SEQ + q0 + q) * SEQ + kt * KB + c * 8];
            const float4 v0 = *reinterpret_cast<const float4*>(srcdst);
            const float4 v1 = *reinterpret_cast<const float4*>(srcdst + 4);
            const float sv[8] = {v0.x, v0.y, v0.z, v0.w, v1.x, v1.y, v1.z, v1.w};
            const float rm = rms[q];
            const float rinv = 1.0f / rls[q];
            const int mq = mqs[q];
            float p[8];
            #pragma unroll
            for (int i = 0; i < 8; ++i) {
                const int mk = mask[b * SEQ + kt * KB + c * 8 + i];
                float pv = expf(sv[i] - rm) * rinv;
                pv = (mq && mk) ? pv : 0.f;
                p[i] = pv;
                Ps[q][c * 8 + i] = pv;
            }
            *reinterpret_cast<float4*>(srcdst) = make_float4(p[0], p[1], p[2], p[3]);
            *reinterpret_cast<float4*>(srcdst + 4) = make_float4(p[4], p[5], p[6], p[7]);
        }
        {
            const int row = tid >> 2;
            const int c0 = (tid & 3) * 16;
            const float* src = &vbuf[((size_t)bh * SEQ + kt * KB + row) * DKH + c0];
            const float4 v0 = *reinterpret_cast<const float4*>(src);
            const float4 v1 = *reinterpret_cast<const float4*>(src + 4);
            const float4 v2 = *reinterpret_cast<const float4*>(src + 8);
            const float4 v3 = *reinterpret_cast<const float4*>(src + 12);
            Vs[row][c0 + 0] = v0.x;  Vs[row][c0 + 1] = v0.y;
            Vs[row][c0 + 2] = v0.z;  Vs[row][c0 + 3] = v0.w;
            Vs[row][c0 + 4] = v1.x;  Vs[row][c0 + 5] = v1.y;
            Vs[row][c0 + 6] = v1.z;  Vs[row][c0 + 7] = v1.w;
            Vs[row][c0 + 8] = v2.x;  Vs[row][c0 + 9] = v2.y;
            Vs[row][c0 + 10] = v2.z; Vs[row][c0 + 11] = v2.w;
            Vs[row][c0 + 12] = v3.x; Vs[row][c0 + 13] = v3.y;
            Vs[row][c0 + 14] = v3.z; Vs[row][c0 + 15] = v3.w;
        }
        __syncthreads();

        #pragma unroll 8
        for (int kk = 0; kk < KB; ++kk) {
            const float pb = Ps[q][kk];
            #pragma unroll
            for (int j = 0; j < 8; ++j)
                xacc[j] = fmaf(pb, Vs[kk][db + j], xacc[j]);
        }
    }

    float* dst = &xbuf[((size_t)(b * SEQ + q0 + q)) * DMODEL + h * DKH + db];
    *reinterpret_cast<float4*>(dst) = make_float4(xacc[0], xacc[1], xacc[2], xacc[3]);
    *reinterpret_cast<float4*>(dst + 4) = make_float4(xacc[4], xacc[5], xacc[6], xacc[7]);
}

// ---------------------------------------------------------------------------
extern "C" void kernel_launch(void* const* d_in, const int* in_sizes, int n_in,
                              void* d_out, int out_size, void* d_ws, size_t ws_size,
                              hipStream_t stream) {
    (void)in_sizes; (void)n_in; (void)out_size; (void)ws_size;

    const float* query = (const float*)d_in[0];
    const float* key   = (const float*)d_in[1];
    const float* value = (const float*)d_in[2];
    const int*   mask  = (const int*)d_in[3];
    const float* Wq    = (const float*)d_in[4];
    const float* bq    = (const float*)d_in[5];
    const float* Wo    = (const float*)d_in[6];
    const float* bo    = (const float*)d_in[7];

    float* out = (float*)d_out;                                    // (8,1024,1024)
    float* pattn = out + (size_t)BATCH * SEQ * DMODEL;             // (8,16,1024,1024)

    float* ws = (float*)d_ws;
    const size_t qkv_elems = (size_t)BATCH * NHEADS * SEQ * DKH;   // 8.39M
    float* qb = ws;
    float* kb = ws + qkv_elems;
    float* vb = ws + 2 * qkv_elems;
    float* rowmax = ws + 3 * qkv_elems;
    float* rowsum = rowmax + (size_t)BATCH * NHEADS * SEQ;
    float* xb = qb;   // q is dead after attn_score_kernel; reuse for x

    const dim3 gblk(DMODEL / BN, MROWS / BM);   // (16, 128)

    // Projections (all use Wq/bq, per the reference), written in (b,H,s,dk).
    gemm_bias_kernel<<<gblk, 256, 0, stream>>>(query, Wq, bq, qb, 1);
    gemm_bias_kernel<<<gblk, 256, 0, stream>>>(key,   Wq, bq, kb, 1);
    gemm_bias_kernel<<<gblk, 256, 0, stream>>>(value, Wq, bq, vb, 1);

    const int ablocks = BATCH * NHEADS * (SEQ / QB);   // 4096
    attn_score_kernel<<<ablocks, 256, 0, stream>>>(qb, kb, mask, pattn, rowmax, rowsum);
    attn_pv_kernel<<<ablocks, 256, 0, stream>>>(vb, mask, pattn, rowmax, rowsum, xb);

    // Output projection: out = x @ Wo^T + bo (row-major).
    gemm_bias_kernel<<<gblk, 256, 0, stream>>>(xb, Wo, bo, out, 0);
}

// Round 2
// 660.755 us; speedup vs baseline: 4.5787x; 4.5787x over previous
//
#include <hip/hip_runtime.h>
#include <cstddef>
#include <cstdint>

#define BATCH   8
#define SEQ     1024
#define DMODEL  1024
#define NHEADS  16
#define DKH     64

typedef __attribute__((ext_vector_type(8))) short bf16x8;
typedef __attribute__((ext_vector_type(4))) short s16x4;
typedef __attribute__((ext_vector_type(4))) float f32x4;

#define MFMA16(a,b,c) __builtin_amdgcn_mfma_f32_16x16x32_bf16(a,b,c,0,0,0)

__device__ __forceinline__ unsigned short f2bf(float f) {
    uint32_t u = __float_as_uint(f);
    u += 0x7fffu + ((u >> 16) & 1u);          // round-to-nearest-even
    return (unsigned short)(u >> 16);
}
__device__ __forceinline__ float bf2f(unsigned short s) {
    return __uint_as_float(((uint32_t)s) << 16);
}

// ---------------------------------------------------------------------------
// Split-convert f32 -> bf16 hi (+ optional lo residual). 4 elems/thread.
// ---------------------------------------------------------------------------
__global__ void cvt_split(const float* __restrict__ src, unsigned short* __restrict__ hi,
                          unsigned short* __restrict__ lo, int n4)
{
    const int i = blockIdx.x * blockDim.x + threadIdx.x;
    if (i >= n4) return;
    const f32x4 v = ((const f32x4*)src)[i];
    s16x4 h4, l4;
    #pragma unroll
    for (int e = 0; e < 4; ++e) {
        const unsigned short hh = f2bf(v[e]);
        h4[e] = (short)hh;
        l4[e] = (short)f2bf(v[e] - bf2f(hh));
    }
    ((s16x4*)hi)[i] = h4;
    if (lo) ((s16x4*)lo)[i] = l4;
}

// ---------------------------------------------------------------------------
// MFMA GEMM: C = A(MxK) * W^T + bias.  W is [N][K] row-major (pre-split bf16).
// NTERMS==3: A is f32 global, split hi/lo on the fly; 3-term MFMA (~f32 acc).
// NTERMS==1: A is plain bf16; 1-term.
// OUTMODE 0: bf16 out in [b,h,s,dk] layout (hi + optional lo residual).
// OUTMODE 2: f32 out row-major [M][N].
// 128x128 tile, BK=32, 4 waves (2x2 of 64x64), padded LDS (bank-conflict-free).
// ---------------------------------------------------------------------------
#define GBM 128
#define GBN 128
#define GBK 32
#define GLDK 40    // 32 + 8 pad (16B-aligned rows, 2-way banks only)

template<int NTERMS, int OUTMODE>
__global__ __launch_bounds__(256)
void gemm_mfma(const float* __restrict__ Af, const unsigned short* __restrict__ Ab,
               const unsigned short* __restrict__ Whi, const unsigned short* __restrict__ Wlo,
               const float* __restrict__ bias,
               unsigned short* __restrict__ Ohi, unsigned short* __restrict__ Olo,
               float* __restrict__ Of)
{
    __shared__ unsigned short sAh[GBM * GLDK];
    __shared__ unsigned short sWh[GBM * GLDK];
    __shared__ unsigned short sAl[NTERMS == 3 ? GBM * GLDK : 64];
    __shared__ unsigned short sWl[NTERMS == 3 ? GBM * GLDK : 64];

    const int tid = threadIdx.x, lane = tid & 63, wid = tid >> 6;
    const int m0 = blockIdx.y * GBM, n0 = blockIdx.x * GBN;
    const int wm = (wid >> 1) * 64, wn = (wid & 1) * 64;

    f32x4 acc[4][4] = {};

    for (int k0 = 0; k0 < DMODEL; k0 += GBK) {
        __syncthreads();
        #pragma unroll
        for (int c = 0; c < 2; ++c) {
            const int id = tid * 2 + c;
            const int row = id >> 2, col = (id & 3) * 8;
            if (NTERMS == 3) {
                const float* g = &Af[(size_t)(m0 + row) * DMODEL + k0 + col];
                const f32x4 u = *(const f32x4*)g;
                const f32x4 v = *(const f32x4*)(g + 4);
                bf16x8 h8, l8;
                #pragma unroll
                for (int e = 0; e < 4; ++e) {
                    const unsigned short hh = f2bf(u[e]);
                    h8[e] = (short)hh; l8[e] = (short)f2bf(u[e] - bf2f(hh));
                }
                #pragma unroll
                for (int e = 0; e < 4; ++e) {
                    const unsigned short hh = f2bf(v[e]);
                    h8[4 + e] = (short)hh; l8[4 + e] = (short)f2bf(v[e] - bf2f(hh));
                }
                *(bf16x8*)&sAh[row * GLDK + col] = h8;
                *(bf16x8*)&sAl[row * GLDK + col] = l8;
                *(bf16x8*)&sWh[row * GLDK + col] = *(const bf16x8*)&Whi[(size_t)(n0 + row) * DMODEL + k0 + col];
                *(bf16x8*)&sWl[row * GLDK + col] = *(const bf16x8*)&Wlo[(size_t)(n0 + row) * DMODEL + k0 + col];
            } else {
                *(bf16x8*)&sAh[row * GLDK + col] = *(const bf16x8*)&Ab[(size_t)(m0 + row) * DMODEL + k0 + col];
                *(bf16x8*)&sWh[row * GLDK + col] = *(const bf16x8*)&Whi[(size_t)(n0 + row) * DMODEL + k0 + col];
            }
        }
        __syncthreads();

        bf16x8 ah[4], bh_[4], al[4], bl_[4];
        #pragma unroll
        for (int m = 0; m < 4; ++m)
            ah[m] = *(const bf16x8*)&sAh[(wm + m * 16 + (lane & 15)) * GLDK + (lane >> 4) * 8];
        #pragma unroll
        for (int n = 0; n < 4; ++n)
            bh_[n] = *(const bf16x8*)&sWh[(wn + n * 16 + (lane & 15)) * GLDK + (lane >> 4) * 8];
        if (NTERMS == 3) {
            #pragma unroll
            for (int m = 0; m < 4; ++m)
                al[m] = *(const bf16x8*)&sAl[(wm + m * 16 + (lane & 15)) * GLDK + (lane >> 4) * 8];
            #pragma unroll
            for (int n = 0; n < 4; ++n)
                bl_[n] = *(const bf16x8*)&sWl[(wn + n * 16 + (lane & 15)) * GLDK + (lane >> 4) * 8];
        }
        #pragma unroll
        for (int m = 0; m < 4; ++m)
            #pragma unroll
            for (int n = 0; n < 4; ++n) {
                acc[m][n] = MFMA16(ah[m], bh_[n], acc[m][n]);
                if (NTERMS == 3) {
                    acc[m][n] = MFMA16(ah[m], bl_[n], acc[m][n]);
                    acc[m][n] = MFMA16(al[m], bh_[n], acc[m][n]);
                }
            }
    }

    #pragma unroll
    for (int n = 0; n < 4; ++n) {
        const int col = n0 + wn + n * 16 + (lane & 15);
        const float bv = bias[col];
        #pragma unroll
        for (int m = 0; m < 4; ++m) {
            #pragma unroll
            for (int j = 0; j < 4; ++j) {
                const int row = m0 + wm + m * 16 + (lane >> 4) * 4 + j;
                const float f = acc[m][n][j] + bv;
                if (OUTMODE == 0) {
                    const int b = row >> 10, s = row & 1023;
                    const int h = col >> 6, di = col & 63;
                    const size_t idx = (((size_t)(b * NHEADS + h)) * SEQ + s) * DKH + di;
                    const unsigned short hh = f2bf(f);
                    Ohi[idx] = hh;
                    if (Olo) Olo[idx] = f2bf(f - bf2f(hh));
                } else {
                    Of[(size_t)row * DMODEL + col] = f;
                }
            }
        }
    }
}

// ---------------------------------------------------------------------------
// Transpose V: [b,h,s,dk] bf16 -> [b,h,dk,s] bf16 (64x64 tiles).
// ---------------------------------------------------------------------------
__global__ __launch_bounds__(256)
void transpose_v(const unsigned short* __restrict__ vb, unsigned short* __restrict__ vt)
{
    const int bh = blockIdx.x >> 4, st = blockIdx.x & 15, s0 = st * 64;
    __shared__ unsigned short t[64][72];
    const int tid = threadIdx.x;
    #pragma unroll
    for (int c = 0; c < 2; ++c) {
        const int id = tid * 2 + c, row = id >> 3, col = (id & 7) * 8;
        *(bf16x8*)&t[row][col] = *(const bf16x8*)&vb[((size_t)bh * SEQ + s0 + row) * DKH + col];
    }
    __syncthreads();
    #pragma unroll
    for (int c = 0; c < 2; ++c) {
        const int id = tid * 2 + c, d = id >> 3, so = (id & 7) * 8;
        bf16x8 o;
        #pragma unroll
        for (int j = 0; j < 8; ++j) o[j] = (short)t[so + j][d];
        *(bf16x8*)&vt[((size_t)bh * DKH + d) * SEQ + s0 + so] = o;
    }
}

// ---------------------------------------------------------------------------
// Fused attention: per block = (b,h, 64 q-rows). 4 waves x 16 q-rows each.
// Pass 1: QK^T (3-term split MFMA) -> online row max/sum (registers).
// Pass 2: recompute QK^T -> p = exp(s-m)/l * mask -> write p_attn f32 once
//         (coalesced via LDS) -> P bf16 A-frags -> PV MFMA -> x bf16.
// ---------------------------------------------------------------------------
#define AQ  64
#define ALD 72

__global__ __launch_bounds__(256)
void attn_fused(const unsigned short* __restrict__ qhi, const unsigned short* __restrict__ qlo,
                const unsigned short* __restrict__ khi, const unsigned short* __restrict__ klo,
                const unsigned short* __restrict__ vt, const int* __restrict__ mask,
                float* __restrict__ pattn, unsigned short* __restrict__ xb)
{
    const int blk = blockIdx.x;
    const int qt = blk & 15, bh = blk >> 4;
    const int b = bh >> 4, h = bh & 15;
    const int q0 = qt * AQ;
    const int tid = threadIdx.x, lane = tid & 63, wid = tid >> 6;

    __shared__ unsigned short sQh[AQ * ALD], sQl[AQ * ALD];
    __shared__ unsigned short sKh[64 * ALD], sKl[64 * ALD];
    __shared__ unsigned short sVt[64 * ALD];
    __shared__ float sP[4][16 * 68];
    __shared__ int smq[AQ], smk[64];

    // ---- load Q tile (hi/lo) ----
    #pragma unroll
    for (int c = 0; c < 2; ++c) {
        const int id = tid * 2 + c, row = id >> 3, col = (id & 7) * 8;
        const size_t g = ((size_t)bh * SEQ + q0 + row) * DKH + col;
        *(bf16x8*)&sQh[row * ALD + col] = *(const bf16x8*)&qhi[g];
        *(bf16x8*)&sQl[row * ALD + col] = *(const bf16x8*)&qlo[g];
    }
    if (tid < AQ) smq[tid] = mask[b * SEQ + q0 + tid];
    __syncthreads();

    // hoisted Q fragments + q-row masks
    const int qrow = wid * 16 + (lane & 15);
    bf16x8 aqh[2], aql[2];
    #pragma unroll
    for (int ks = 0; ks < 2; ++ks) {
        aqh[ks] = *(const bf16x8*)&sQh[qrow * ALD + ks * 32 + (lane >> 4) * 8];
        aql[ks] = *(const bf16x8*)&sQl[qrow * ALD + ks * 32 + (lane >> 4) * 8];
    }
    int mqr[4];
    #pragma unroll
    for (int j = 0; j < 4; ++j) mqr[j] = smq[wid * 16 + (lane >> 4) * 4 + j];

    float rm[4], rl[4];
    #pragma unroll
    for (int j = 0; j < 4; ++j) { rm[j] = -3.0e38f; rl[j] = 0.f; }

    // ================= PASS 1: online softmax stats =================
    for (int kt = 0; kt < SEQ / 64; ++kt) {
        __syncthreads();
        #pragma unroll
        for (int c = 0; c < 2; ++c) {
            const int id = tid * 2 + c, row = id >> 3, col = (id & 7) * 8;
            const size_t g = ((size_t)bh * SEQ + kt * 64 + row) * DKH + col;
            *(bf16x8*)&sKh[row * ALD + col] = *(const bf16x8*)&khi[g];
            *(bf16x8*)&sKl[row * ALD + col] = *(const bf16x8*)&klo[g];
        }
        if (tid < 64) smk[tid] = mask[b * SEQ + kt * 64 + tid];
        __syncthreads();

        f32x4 acc4[4] = {};
        #pragma unroll
        for (int ks = 0; ks < 2; ++ks)
            #pragma unroll
            for (int n = 0; n < 4; ++n) {
                const bf16x8 kh = *(const bf16x8*)&sKh[(n * 16 + (lane & 15)) * ALD + ks * 32 + (lane >> 4) * 8];
                const bf16x8 kl = *(const bf16x8*)&sKl[(n * 16 + (lane & 15)) * ALD + ks * 32 + (lane >> 4) * 8];
                acc4[n] = MFMA16(aqh[ks], kh, acc4[n]);
                acc4[n] = MFMA16(aqh[ks], kl, acc4[n]);
                acc4[n] = MFMA16(aql[ks], kh, acc4[n]);
            }

        int mkc[4];
        #pragma unroll
        for (int n = 0; n < 4; ++n) mkc[n] = smk[n * 16 + (lane & 15)];

        #pragma unroll
        for (int j = 0; j < 4; ++j) {
            float s[4];
            #pragma unroll
            for (int n = 0; n < 4; ++n)
                s[n] = (mqr[j] && mkc[n]) ? acc4[n][j] * 0.125f : -1.0e9f;
            float t = fmaxf(fmaxf(s[0], s[1]), fmaxf(s[2], s[3]));
            #pragma unroll
            for (int o = 1; o < 16; o <<= 1) t = fmaxf(t, __shfl_xor(t, o, 16));
            const float nm = fmaxf(rm[j], t);
            float ps = 0.f;
            #pragma unroll
            for (int n = 0; n < 4; ++n) ps += __expf(s[n] - nm);
            #pragma unroll
            for (int o = 1; o < 16; o <<= 1) ps += __shfl_xor(ps, o, 16);
            rl[j] = rl[j] * __expf(rm[j] - nm) + ps;
            rm[j] = nm;
        }
    }

    float rinv[4];
    #pragma unroll
    for (int j = 0; j < 4; ++j) rinv[j] = 1.0f / rl[j];

    // ================= PASS 2: p write + PV =================
    f32x4 oacc[4] = {};
    for (int kt = 0; kt < SEQ / 64; ++kt) {
        __syncthreads();
        #pragma unroll
        for (int c = 0; c < 2; ++c) {
            const int id = tid * 2 + c, row = id >> 3, col = (id & 7) * 8;
            const size_t g = ((size_t)bh * SEQ + kt * 64 + row) * DKH + col;
            *(bf16x8*)&sKh[row * ALD + col] = *(const bf16x8*)&khi[g];
            *(bf16x8*)&sKl[row * ALD + col] = *(const bf16x8*)&klo[g];
            const size_t gv = ((size_t)bh * DKH + row) * SEQ + kt * 64 + col;
            *(bf16x8*)&sVt[row * ALD + col] = *(const bf16x8*)&vt[gv];
        }
        if (tid < 64) smk[tid] = mask[b * SEQ + kt * 64 + tid];
        __syncthreads();

        f32x4 acc4[4] = {};
        #pragma unroll
        for (int ks = 0; ks < 2; ++ks)
            #pragma unroll
            for (int n = 0; n < 4; ++n) {
                const bf16x8 kh = *(const bf16x8*)&sKh[(n * 16 + (lane & 15)) * ALD + ks * 32 + (lane >> 4) * 8];
                const bf16x8 kl = *(const bf16x8*)&sKl[(n * 16 + (lane & 15)) * ALD + ks * 32 + (lane >> 4) * 8];
                acc4[n] = MFMA16(aqh[ks], kh, acc4[n]);
                acc4[n] = MFMA16(aqh[ks], kl, acc4[n]);
                acc4[n] = MFMA16(aql[ks], kh, acc4[n]);
            }

        #pragma unroll
        for (int n = 0; n < 4; ++n) {
            const int mk = smk[n * 16 + (lane & 15)];
            #pragma unroll
            for (int j = 0; j < 4; ++j) {
                const int live = (mqr[j] && mk);
                const float sv = live ? acc4[n][j] * 0.125f : -1.0e9f;
                float p = __expf(sv - rm[j]) * rinv[j];
                if (!live) p = 0.f;
                sP[wid][((lane >> 4) * 4 + j) * 68 + n * 16 + (lane & 15)] = p;
            }
        }
        __syncthreads();   // sP visible to all lanes (and other phases done)

        // coalesced f32 p_attn write (16 rows x 256B per wave)
        #pragma unroll
        for (int rr = 0; rr < 4; ++rr) {
            const int prow = rr * 4 + (lane >> 4);
            const int pcol = (lane & 15) * 4;
            const f32x4 pv = *(const f32x4*)&sP[wid][prow * 68 + pcol];
            *(f32x4*)&pattn[((size_t)bh * SEQ + q0 + wid * 16 + prow) * SEQ + kt * 64 + pcol] = pv;
        }

        // P bf16 A-frags -> PV
        #pragma unroll
        for (int ks = 0; ks < 2; ++ks) {
            const float* pp = &sP[wid][(lane & 15) * 68 + ks * 32 + (lane >> 4) * 8];
            const f32x4 p0 = *(const f32x4*)pp;
            const f32x4 p1 = *(const f32x4*)(pp + 4);
            bf16x8 ap;
            #pragma unroll
            for (int e = 0; e < 4; ++e) { ap[e] = (short)f2bf(p0[e]); ap[4 + e] = (short)f2bf(p1[e]); }
            #pragma unroll
            for (int n = 0; n < 4; ++n) {
                const bf16x8 bv = *(const bf16x8*)&sVt[(n * 16 + (lane & 15)) * ALD + ks * 32 + (lane >> 4) * 8];
                oacc[n] = MFMA16(ap, bv, oacc[n]);
            }
        }
    }

    // x out: bf16 row-major [b*SEQ + q][DMODEL]
    #pragma unroll
    for (int n = 0; n < 4; ++n)
        #pragma unroll
        for (int j = 0; j < 4; ++j) {
            const int row = q0 + wid * 16 + (lane >> 4) * 4 + j;
            const int col = h * DKH + n * 16 + (lane & 15);
            xb[(size_t)(b * SEQ + row) * DMODEL + col] = f2bf(oacc[n][j]);
        }
}

// ---------------------------------------------------------------------------
extern "C" void kernel_launch(void* const* d_in, const int* in_sizes, int n_in,
                              void* d_out, int out_size, void* d_ws, size_t ws_size,
                              hipStream_t stream) {
    (void)in_sizes; (void)n_in; (void)out_size; (void)ws_size;

    const float* query = (const float*)d_in[0];
    const float* key   = (const float*)d_in[1];
    const float* value = (const float*)d_in[2];
    const int*   mask  = (const int*)d_in[3];
    const float* Wq    = (const float*)d_in[4];
    const float* bq    = (const float*)d_in[5];
    const float* Wo    = (const float*)d_in[6];
    const float* bo    = (const float*)d_in[7];

    float* out   = (float*)d_out;                               // (8,1024,1024)
    float* pattn = out + (size_t)BATCH * SEQ * DMODEL;          // (8,16,1024,1024)

    const size_t NE = (size_t)BATCH * SEQ * DMODEL;             // 8.39M elems
    const size_t WE = (size_t)DMODEL * DMODEL;                  // 1.05M elems
    char* w = (char*)d_ws;
    unsigned short* wqhi = (unsigned short*)w;  w += WE * 2;
    unsigned short* wqlo = (unsigned short*)w;  w += WE * 2;
    unsigned short* wohi = (unsigned short*)w;  w += WE * 2;
    unsigned short* qhi  = (unsigned short*)w;  w += NE * 2;
    unsigned short* qlo  = (unsigned short*)w;  w += NE * 2;
    unsigned short* khi  = (unsigned short*)w;  w += NE * 2;
    unsigned short* klo  = (unsigned short*)w;  w += NE * 2;
    unsigned short* vbh  = (unsigned short*)w;  w += NE * 2;
    unsigned short* vt   = (unsigned short*)w;  w += NE * 2;
    unsigned short* xb   = (unsigned short*)w;  w += NE * 2;

    // weight splits
    const int wn4 = (int)(WE / 4);
    cvt_split<<<(wn4 + 255) / 256, 256, 0, stream>>>(Wq, wqhi, wqlo, wn4);
    cvt_split<<<(wn4 + 255) / 256, 256, 0, stream>>>(Wo, wohi, nullptr, wn4);

    const dim3 gblk(DMODEL / GBN, (BATCH * SEQ) / GBM);   // (8, 64)

    // projections (split-precision), outputs in (b,h,s,dk)
    gemm_mfma<3, 0><<<gblk, 256, 0, stream>>>(query, nullptr, wqhi, wqlo, bq, qhi, qlo, nullptr);
    gemm_mfma<3, 0><<<gblk, 256, 0, stream>>>(key,   nullptr, wqhi, wqlo, bq, khi, klo, nullptr);
    gemm_mfma<3, 0><<<gblk, 256, 0, stream>>>(value, nullptr, wqhi, wqlo, bq, vbh, nullptr, nullptr);

    transpose_v<<<BATCH * NHEADS * (SEQ / 64), 256, 0, stream>>>(vbh, vt);

    attn_fused<<<BATCH * NHEADS * (SEQ / AQ), 256, 0, stream>>>(qhi, qlo, khi, klo, vt, mask, pattn, xb);

    // output projection (plain bf16), f32 out
    gemm_mfma<1, 2><<<gblk, 256, 0, stream>>>(nullptr, xb, wohi, nullptr, bo, nullptr, nullptr, out);
}